// Round 9
// baseline (176.362 us; speedup 1.0000x reference)
//
#include <hip/hip_runtime.h>
#include <hip/hip_cooperative_groups.h>
#include <math.h>

// EpsilonState, R17 = single cooperative fused kernel; batch = R12-validated pfPR64q.
//  Ledger across R9-R16: total - batch ~ 70-80us stable => pre_mat ~42, final ~3,
//  inter-launch/dispatch overhead ~25-35us (never attacked). Batch restructures
//  (R13 readlane, R14/R15 register+spill, R16 distributed+spill) all >= R12's 40.3.
//  R17: revert batch math to R12's pfPR64q (VGPR 52, no spill) and fuse all three
//  kernels into ONE hipLaunchCooperativeKernel (guide-blessed) with grid.sync():
//  134 blocks x 1024 thr (1 block/CU, co-resident): blk 0-1 pre_mat -> sync ->
//  blk 2-133 batch (waves 0-3 active RMW exactly as R12; waves 4-15 barrier
//  companions reading only the uniform pivot elem) -> sync -> blk 0 final.
//  LDS = 49.7K (pre_mat) + 37.6K (batch) ~ 87KB < 160KB. Blocksize 1024 caps VGPR<=128.
// Validated pieces unchanged:
//  - Pf([[A,-I],[I,D]]) = Pf(A)*Pf(D+A^-1)  [R3]   - Ainv 1st-order Neumann [R7]
//  - closed-form bidiagonal Minv f(r,c) [R4]       - sigma-shifted pre-Pf (+pi) [R7]

namespace cg = cooperative_groups;

typedef double2 dcx;
typedef float2 cf;
#define PI_ 3.14159265358979323846
// pair-granular swizzle: column-pair index XORed with row(&31), pair stays adjacent
#define SIDX16(i,j) (((i) << 6) | (((((j) >> 1) ^ ((i) & 31)) << 1) | ((j) & 1)))

__device__ __forceinline__ dcx dmk(double re, double im){ dcx c; c.x=re; c.y=im; return c; }
__device__ __forceinline__ dcx dmul(dcx a, dcx b){ return dmk(a.x*b.x - a.y*b.y, a.x*b.y + a.y*b.x); }

__device__ __forceinline__ double bf2d(unsigned short u){
  union { unsigned u; float f; } cv; cv.u = ((unsigned)u) << 16; return (double)cv.f;
}
__device__ __forceinline__ unsigned short d2bf(double v){
  float f = (float)v;
  union { float f; unsigned u; } cv; cv.f = f;
  unsigned u = cv.u;
  u = (u + 0x7FFFu + ((u >> 16) & 1u)) >> 16;
  return (unsigned short)u;
}
// mode: 0 = bf16, 1 = float32, 2 = float64 (probe buffer first element is +-1.0)
__device__ __forceinline__ int detect_mode(const void* p){
  unsigned w0 = *(const unsigned*)p;
  if ((w0 & 0x7FFFFFFFu) == 0x3F800000u) return 1;
  if ((w0 & 0x7FFFu) == 0x3F80u) return 0;
  return 2;
}
__device__ __forceinline__ double ldv(const void* p, int idx, int mode){
  if (mode == 0) return bf2d(((const unsigned short*)p)[idx]);
  if (mode == 1) return (double)((const float*)p)[idx];
  return ((const double*)p)[idx];
}

// ---------------- 64x64 fp32 matmul in LDS: C = scale*A*B (1024 threads) ----------
__device__ void mm64f_1024(float* C, const float* A, const float* B, float scale){
  const int t = threadIdx.x;
  #pragma unroll
  for (int q = 0; q < 4; ++q) {
    int idx = t + (q << 10);
    int i = idx >> 6, j = idx & 63;
    const float* Ar = A + i*64;
    float acc = 0.f;
    #pragma unroll 8
    for (int k = 0; k < 64; ++k) acc += Ar[k] * B[k*64 + j];
    C[idx] = scale * acc;
  }
}

// ---------------- pre_mat body: px = blockIdx (0,1), 1024 threads (R9-validated) ---
__device__ void pre_mat_body(int px,
    const void* __restrict__ h1, const void* __restrict__ h2, const void* __restrict__ s0,
    cf* Apx, cf* Czpx, cf* AinvG, dcx* lec_base)
{
  const int t = threadIdx.x;
  const int lane = t & 63, wv = t >> 6;          // 16 waves
  const float is2 = 0.70710678118654752440f;
  const int mode = detect_mode(s0);
  const void* H = (px == 0) ? h1 : h2;

  __shared__ __align__(16) unsigned char SH[49664];
  float* Kf = (float*)SH;                    // 16384: K -> (later) RM
  float* Ef = (float*)(SH + 16384);          // 16384: K^2/2 -> E -> M|T1
  cf*   Rc  = (cf*)(SH + 32768);             // 16384: R (64x32)
  cf*   Msl = (cf*)(SH + 16384);             // 8192: M (alias Ef lower)
  cf*   Tsl = (cf*)(SH + 16384 + 8192);      // 8192: T1 -> Mi
  cf*   RMc = (cf*)SH;                       // 16384: RM (alias Kf, after Cz write)
  cf*   ALDS = (cf*)(SH + 16384);            // 32768: A copy (over Ef+Rc, post-RM)
  double* ssh = (double*)(SH + 49152);       // 256
  double* red = (double*)(SH + 49408);       // 128 = 16 doubles (one per wave)
  __shared__ double le_sh;

  if (t < 32) {
    double a = ldv(s0, t, mode);
    double b = ldv(s0, (t + 1) & 31, mode);
    double zz = a * b;
    double s = (zz >= 0.0) ? 1.0 : -1.0;
    if (t == 31) s = (px == 0) ? -s : s;     // sgn[-1] *= -PX
    ssh[t] = s;
  }
  double k2 = 0.0;
  for (int e = t; e < 4096; e += 1024) {
    int i = e >> 6, j = e & 63;
    float kv = (float)(0.5 * (ldv(H, i*64 + j, mode) - ldv(H, j*64 + i, mode)));
    Kf[e] = kv;
    k2 += (double)kv * (double)kv;
  }
  #pragma unroll
  for (int off = 32; off > 0; off >>= 1) k2 += __shfl_down(k2, off, 64);
  if (lane == 0) red[wv] = k2;
  __syncthreads();
  if (t == 0) {
    double acc = 0.0;
    #pragma unroll
    for (int w = 0; w < 16; ++w) acc += red[w];
    le_sh = -acc / 16.0;
  }
  mm64f_1024(Ef, Kf, Kf, 0.5f);
  __syncthreads();
  for (int e = t; e < 4096; e += 1024) {
    int i = e >> 6, j = e & 63;
    Ef[e] += Kf[e] + ((i == j) ? 1.f : 0.f);   // E = I + K + K^2/2
  }
  __syncthreads();
  for (int e = t; e < 2048; e += 1024) {       // R = E v
    int r = e >> 5, k = e & 31;
    int a = 2*k + 1, b2 = (2*k + 2) & 63;
    cf z; z.x = Ef[r*64 + b2] * is2; z.y = -(float)ssh[k] * Ef[r*64 + a] * is2;
    Rc[e] = z;
  }
  __syncthreads();
  {                                            // M = v^H R (1024 elems, 1/thread)
    int e = t;
    int c = e >> 5, k = e & 31;
    int a = 2*c + 1, b2 = (2*c + 2) & 63;
    cf Ra = Rc[a*32 + k], Rb = Rc[b2*32 + k];
    float s = (float)ssh[c];
    cf z; z.x = (-Ra.y*s + Rb.x)*is2; z.y = (Ra.x*s + Rb.y)*is2;
    Msl[e] = z;
  }
  __syncthreads();
  {                                            // T1 = (M-I)^2 (1 elem/thread)
    int e = t;
    int i = e >> 5, j = e & 31;
    float ar = 0.f, ai = 0.f;
    for (int k = 0; k < 32; ++k) {
      cf d1 = Msl[i*32 + k]; if (k == i) d1.x -= 1.f;
      cf d2 = Msl[k*32 + j]; if (k == j) d2.x -= 1.f;
      ar += d1.x*d2.x - d1.y*d2.y;
      ai += d1.x*d2.y + d1.y*d2.x;
    }
    cf z; z.x = ar; z.y = ai;
    __syncthreads();
    // Mi = 2I - M + T1 (Neumann)
    cf m = Msl[e];
    cf w; w.x = ((i == j) ? 2.f : 0.f) - m.x + z.x; w.y = -m.y + z.y;
    Tsl[e] = w;
  }
  for (int e = t; e < 4096; e += 1024) {       // Cz = -K/2 + i*Dz
    int r = e >> 6, c = e & 63;
    float vr = -0.5f * Kf[e];
    float vi = 0.f;
    if ((r & 1) && c == ((r + 1) & 63)) vi = (float)ssh[r >> 1];
    else if ((c & 1) && r == ((c + 1) & 63)) vi = -(float)ssh[c >> 1];
    cf z; z.x = vr; z.y = vi;
    Czpx[(size_t)px*4096 + e] = z;
  }
  __syncthreads();
  for (int e = t; e < 2048; e += 1024) {       // RM = R * Mi (into Kf slot)
    int r = e >> 5, j = e & 31;
    float ar = 0.f, ai = 0.f;
    for (int k = 0; k < 32; ++k) {
      cf a = Rc[r*32 + k], b = Tsl[k*32 + j];
      ar += a.x*b.x - a.y*b.y;
      ai += a.x*b.y + a.y*b.x;
    }
    cf z; z.x = ar; z.y = ai;
    RMc[e] = z;
  }
  __syncthreads();
  for (int e = t; e < 4096; e += 1024) {       // A = antisym(Ghz), v-sparse form
    int r = e >> 6, j = e & 63;
    int cj, cr; cf uj, ur;
    if (j & 1) { cj = j >> 1; uj.x = 0.f; uj.y = (float)ssh[cj] * is2; }
    else { cj = ((j >> 1) + 31) & 31; uj.x = is2; uj.y = 0.f; }
    if (r & 1) { cr = r >> 1; ur.x = 0.f; ur.y = (float)ssh[cr] * is2; }
    else { cr = ((r >> 1) + 31) & 31; ur.x = is2; ur.y = 0.f; }
    cf m1 = RMc[r*32 + cj], m2 = RMc[j*32 + cr];
    cf t1; t1.x = m1.x*uj.x - m1.y*uj.y; t1.y = m1.x*uj.y + m1.y*uj.x;
    cf t2; t2.x = m2.x*ur.x - m2.y*ur.y; t2.y = m2.x*ur.y + m2.y*ur.x;
    cf z; z.x = t2.x - t1.x; z.y = t2.y - t1.y;
    Apx[(size_t)px*4096 + e] = z;
    ALDS[e] = z;
  }
  __syncthreads();
  // Ainv = Dz - a_r*a_c*Delta[pmap r][pmap c]; Delta = A - Dz; Dz(r,c) = i*a_r at c==pmap(r)
  for (int e = t; e < 4096; e += 1024) {
    int r = e >> 6, c = e & 63;
    int pr = (r & 1) ? ((r + 1) & 63) : ((r - 1) & 63);
    int pc = (c & 1) ? ((c + 1) & 63) : ((c - 1) & 63);
    float ar = (r & 1) ? (float)ssh[r >> 1] : -(float)ssh[((r - 1) & 63) >> 1];
    float ac = (c & 1) ? (float)ssh[c >> 1] : -(float)ssh[((c - 1) & 63) >> 1];
    cf Ap = ALDS[pr*64 + pc];
    cf d; d.x = Ap.x; d.y = Ap.y;
    if (c == pr) d.y += ar;
    float f = -ar * ac;
    cf z; z.x = f*d.x; z.y = f*d.y;
    if (c == pr) z.y += ar;                    // + Dz(r,c) = i*a_r
    AinvG[(size_t)px*4096 + e] = z;
  }
  if (t == 0) {
    double ps = 1.0;
    for (int k = 0; k < 32; ++k) ps *= ssh[k];
    double phDz = (ps > 0.0) ? PI_ : 0.0;      // Pf(Dz) = -prod(s)
    lec_base[px] = dmk(le_sh, phDz);
  }
  __threadfence();                             // publish before grid.sync
}

// ---------------- Parlett-Reid slog-Pfaffian, R12 path at 16 waves -----------------
// Waves 0-3: identical to R12's pfPR64q (40.3us validated). Waves 4-15: barrier
// companions — read only the uniform pivot element to stay branch-convergent.
__device__ void pfPR64q16(cf* S, float4* ubuf, double* lab_out, double* ph_out){
  const int t = threadIdx.x;
  const int l = t & 63;
  const int w = t >> 6;                        // 0..15
  const bool act = (w < 4);
  const int lmask = l & 31;
  const int rbase = l << 6;
  double prodr = 1.0, prodi = 0.0;
  int neg = 0, zflag = 0;
  for (int p = 0; p < 31; ++p) {
    const int l0 = 2*p;
    __syncthreads();                           // publish prior step / build
    cf b1, b2, a;
    if (act) {
      b1 = S[SIDX16(l, l0)];
      b2 = S[SIDX16(l, l0+1)];
      a.x = __shfl(b2.x, l0, 64); a.y = __shfl(b2.y, l0, 64);
    } else {
      a = S[SIDX16(l0, l0+1)];                 // uniform-addr broadcast read
    }
    float am2 = a.x*a.x + a.y*a.y;
    if (am2 < 1e-4f) {                         // uniform rare path: pivot search
      if (!act) b1 = S[SIDX16(l, l0)];
      float val = (l >= l0+1) ? (b1.x*b1.x + b1.y*b1.y) : 0.f;
      unsigned pk = (__float_as_uint(val) & 0xFFFFFFC0u) | (unsigned)l;
      #pragma unroll
      for (int off = 32; off > 0; off >>= 1) {
        unsigned o = (unsigned)__shfl_xor((int)pk, off, 64);
        if (o > pk) pk = o;
      }
      int q = (int)(pk & 63u);                 // identical in all waves
      if (q > l0+1) {
        __syncthreads();
        if (t < 64) {                          // physical row swap l0+1 <-> q
          cf r1 = S[SIDX16(l0+1, t)], r2 = S[SIDX16(q, t)];
          S[SIDX16(l0+1, t)] = r2; S[SIDX16(q, t)] = r1;
        }
        __syncthreads();
        if (t < 64) {                          // physical col swap
          cf u1 = S[SIDX16(t, l0+1)], u2 = S[SIDX16(t, q)];
          S[SIDX16(t, l0+1)] = u2; S[SIDX16(t, q)] = u1;
        }
        __syncthreads();
        neg ^= 1;
      }
      if (act) {
        b1 = S[SIDX16(l, l0)]; b2 = S[SIDX16(l, l0+1)];
        a.x = __shfl(b2.x, l0, 64); a.y = __shfl(b2.y, l0, 64);
      } else {
        a = S[SIDX16(l0, l0+1)];
      }
      am2 = a.x*a.x + a.y*a.y;
    }
    {                                          // prod *= a (uniform, all threads)
      double nr = prodr*(double)a.x - prodi*(double)a.y;
      double ni = prodr*(double)a.y + prodi*(double)a.x;
      prodr = nr; prodi = ni;
    }
    if (am2 == 0.f) { zflag = 1; continue; }   // uniform: singular step
    cf w1, w2; w1.x = w1.y = w2.x = w2.y = 0.f;
    if (act) {
      float rcp = 1.f/am2;
      cf iv; iv.x = a.x*rcp; iv.y = -a.y*rcp;
      w1.x = b1.x*iv.x - b1.y*iv.y; w1.y = b1.x*iv.y + b1.y*iv.x;
      w2.x = b2.x*iv.x - b2.y*iv.y; w2.y = b2.x*iv.y + b2.y*iv.x;
      if (w == 0) {
        float4 ub; ub.x = b1.x; ub.y = b1.y; ub.z = b2.x; ub.w = b2.y;
        ubuf[l] = ub;
      }
    }
    __syncthreads();                           // ubuf visible
    if (act) {
      const int lim = l0 + 2;
      const bool rowok = (l >= lim);
      #pragma unroll
      for (int jj = 0; jj < 8; ++jj) {
        int q2 = p + 1 + jj*4 + w;             // this wave's pair index
        int qc = (q2 > 31) ? 31 : q2;          // clamp: address always valid
        float4 ua  = ubuf[2*qc];               // u(j), j = 2*qc (broadcast)
        float4 ubx = ubuf[2*qc + 1];           // u(j+1)
        int idx = rbase | ((qc ^ lmask) << 1); // SIDX16(l, 2*qc)
        float4 cur = *(float4*)(S + idx);
        cur.x += w2.x*ua.x  - w2.y*ua.y  - w1.x*ua.z  + w1.y*ua.w;
        cur.y += w2.x*ua.y  + w2.y*ua.x  - w1.x*ua.w  - w1.y*ua.z;
        cur.z += w2.x*ubx.x - w2.y*ubx.y - w1.x*ubx.z + w1.y*ubx.w;
        cur.w += w2.x*ubx.y + w2.y*ubx.x - w1.x*ubx.w - w1.y*ubx.z;
        if (rowok && q2 <= 31) *(float4*)(S + idx) = cur;
      }
    }
  }
  __syncthreads();
  cf z = S[SIDX16(62, 63)];
  double nr = prodr*(double)z.x - prodi*(double)z.y;
  double ni = prodr*(double)z.y + prodi*(double)z.x;
  if (neg) { nr = -nr; ni = -ni; }
  double m2 = nr*nr + ni*ni;
  if (zflag || m2 == 0.0) { *lab_out = -23000.0; *ph_out = 0.0; }
  else { *lab_out = 0.5*log(m2); *ph_out = atan2(ni, nr); }
}

// ---------------- batch body: pb 0..127 = (px,b); 128..131 = pre-Pfaffians ---------
__device__ void batch_body(int pb,
    const void* __restrict__ x, const cf* __restrict__ Apx, const cf* __restrict__ Czpx,
    const cf* __restrict__ AinvG, dcx* lo, dcx* lecA)
{
  __shared__ __align__(16) unsigned char SHB[36608];
  cf* Sp      = (cf*)SHB;                     // 32768: SIDX16 64x64
  double* ssh = (double*)(SHB + 32768);       // 256
  dcx* rho    = (dcx*)(SHB + 33024);          // 1024
  dcx* uu     = (dcx*)(SHB + 34048);          // 1024
  int* cidx   = (int*)(SHB + 35072);          // 256
  float* pref = (float*)(SHB + 35328);        // 132 (+pad)
  float4* ubuf = (float4*)(SHB + 35472);      // 1024: border broadcast table
  const int t = threadIdx.x;                  // 0..1023
  const double inv_sqrt2 = 0.70710678118654752440;

  if (pb >= 128) {          // pre-Pfaffians, sigma-shifted (det sigma = -1 -> +pi)
    const int idx = pb - 128;
    const cf* src = (idx < 2) ? (Apx + (size_t)idx*4096) : (Czpx + (size_t)(idx-2)*4096);
    for (int e = t; e < 4096; e += 1024) {
      int i = e >> 6, j = e & 63;
      Sp[SIDX16(i, j)] = src[((i + 1) & 63)*64 + ((j + 1) & 63)];
    }
  } else {
    const int px = pb >> 6, b = pb & 63;
    const int mode = detect_mode(x);

    if (t < 32) {
      double a = ldv(x, b*32 + t, mode);
      double b2 = ldv(x, b*32 + ((t + 1) & 31), mode);
      double zz = a * b2;
      double s = (zz >= 0.0) ? 1.0 : -1.0;
      if (t == 31) s = (px == 0) ? -s : s;
      ssh[t] = s;
    }
    __syncthreads();
    if (t < 64) {
      int r = t;
      if (r & 1) rho[r] = dmk(inv_sqrt2, 0.0);
      else {
        int k = r >> 1;
        double pim = -inv_sqrt2;
        if (px == 1 && k == 31) pim = inv_sqrt2;
        rho[r] = dmk(0.0, pim);
      }
      int j = t;
      if (j & 1) { cidx[j] = j >> 1; uu[j] = dmk(0.0, ssh[j >> 1] * inv_sqrt2); }
      else { cidx[j] = ((j >> 1) + 31) & 31; uu[j] = dmk(inv_sqrt2, 0.0); }
    }
    if (t == 0) {
      float pp = 1.f;
      pref[0] = 1.f;
      for (int c = 0; c < 32; ++c) {
        float q = (px == 1 && c == 30) ? 1.f : -1.f;
        pp *= q * (float)ssh[c];
        pref[c + 1] = pp;
      }
    }
    __syncthreads();
    // C = D + Ainv; D[a][b] = rho_b u_a Minv[b/2][c_a] - rho_a u_b Minv[a/2][c_b],
    // Minv[r][c] = -i*f(r,c) closed form (R4/R5-validated pieces).
    for (int e = t; e < 4096; e += 1024) {
      int a = e >> 6, bb = e & 63;
      int r1 = bb >> 1, c1 = cidx[a];
      float f1 = ((c1 < r1) ? -1.f : 1.f) * (((c1 - r1) & 1) ? -1.f : 1.f)
                 * pref[r1] * pref[c1] * (float)ssh[c1];
      int r2 = a >> 1, c2 = cidx[bb];
      float f2 = ((c2 < r2) ? -1.f : 1.f) * (((c2 - r2) & 1) ? -1.f : 1.f)
                 * pref[r2] * pref[c2] * (float)ssh[c2];
      dcx m1 = dmk(0.0, -(double)f1);
      dcx m2 = dmk(0.0, -(double)f2);
      dcx t1 = dmul(dmul(rho[bb], uu[a]), m1);
      dcx t2 = dmul(dmul(rho[a], uu[bb]), m2);
      cf av = AinvG[(size_t)px*4096 + e];
      cf z;
      z.x = (float)((double)av.x + t1.x - t2.x);
      z.y = (float)((double)av.y + t1.y - t2.y);
      Sp[SIDX16(a, bb)] = z;
    }
  }
  double lab, ph;
  pfPR64q16(Sp, ubuf, &lab, &ph);   // entry barrier inside (loop top)
  if (t == 0) {
    if (pb >= 128) lecA[pb - 128] = dmk(lab, ph + PI_);
    else lo[pb] = dmk(lab, ph);
    __threadfence();                // publish before grid.sync
  }
}

// ---------------- final body: block 0, threads < 64 --------------------------------
__device__ void final_body(const void* __restrict__ x, const void* __restrict__ s0,
                           const dcx* __restrict__ lec_base, const dcx* __restrict__ lecA,
                           const dcx* __restrict__ lo, void* __restrict__ out, int out_size)
{
  int b = threadIdx.x;
  if (b >= 64) return;
  const int mode = detect_mode(x);
  double L[2], P[2];
  #pragma unroll
  for (int px = 0; px < 2; ++px) {
    dcx base = lec_base[px], eA = lecA[px], eC = lecA[2 + px], l = lo[px*64 + b];
    L[px] = base.x + eA.x + eC.x + l.x;
    P[px] = base.y + eA.y + eC.y + l.y;
  }
  dcx t1 = dmk(L[1], P[1]);                 // minus
  dcx t2 = dmk(L[0], P[0]);                 // plus
  double v = ldv(x, b*32 + 31, mode) * ldv(s0, 31, mode);
  t2.x += log(fabs(v));
  if (v < 0.0) t2.y += PI_;
  double mr = fmax(t1.x, t2.x);
  double e1 = exp(t1.x - mr), e2 = exp(t2.x - mr);
  double zr = e1 * cos(t1.y) + e2 * cos(t2.y);
  double zi = e1 * sin(t1.y) + e2 * sin(t2.y);
  double outr = mr + 0.5 * log(zr*zr + zi*zi);
  double outi = atan2(zi, zr);
  if (mode == 0) {
    unsigned short* o = (unsigned short*)out;
    if (out_size >= 128) { o[2*b] = d2bf(outr); o[2*b + 1] = d2bf(outi); }
    else o[b] = d2bf(outr);
  } else {
    float* o = (float*)out;
    if (out_size >= 128) { o[2*b] = (float)outr; o[2*b + 1] = (float)outi; }
    else o[b] = (float)outr;
  }
}

// ---------------- fused cooperative kernel -----------------------------------------
__global__ __launch_bounds__(1024, 1) void fused(
    const void* __restrict__ x, const void* __restrict__ s0,
    const void* __restrict__ h1, const void* __restrict__ h2,
    cf* Apx, cf* Czpx, cf* AinvG, dcx* lec_base, dcx* lecA, dcx* lo,
    void* out, int out_size)
{
  cg::grid_group grid = cg::this_grid();
  const int blk = blockIdx.x;
  if (blk < 2) pre_mat_body(blk, h1, h2, s0, Apx, Czpx, AinvG, lec_base);
  grid.sync();
  if (blk >= 2) batch_body(blk - 2, x, Apx, Czpx, AinvG, lo, lecA);
  grid.sync();
  if (blk == 0) final_body(x, s0, lec_base, lecA, lo, out, out_size);
}

extern "C" void kernel_launch(void* const* d_in, const int* in_sizes, int n_in,
                              void* d_out, int out_size, void* d_ws, size_t ws_size,
                              hipStream_t stream)
{
  const void* x  = d_in[0];
  const void* s0 = d_in[1];
  const void* h1 = d_in[2];
  const void* h2 = d_in[3];

  cf*  Apx   = (cf*)d_ws;                   // 2*4096 cf
  cf*  Czpx  = Apx + 8192;                  // 2*4096 cf
  cf*  AinvG = Czpx + 8192;                 // 2*4096 cf
  dcx* lec_base = (dcx*)(AinvG + 8192);     // 2
  dcx* lecA  = lec_base + 2;                // 4
  dcx* lo    = lecA + 4;                    // 128
  // ~0.2 MB of d_ws

  void* kargs[] = {
    (void*)&x, (void*)&s0, (void*)&h1, (void*)&h2,
    (void*)&Apx, (void*)&Czpx, (void*)&AinvG,
    (void*)&lec_base, (void*)&lecA, (void*)&lo,
    (void*)&d_out, (void*)&out_size
  };
  hipLaunchCooperativeKernel((void*)fused, dim3(134), dim3(1024), kargs, 0, stream);
}

// Round 10
// 117.445 us; speedup vs baseline: 1.5017x; 1.5017x over previous
//
#include <hip/hip_runtime.h>
#include <math.h>

// EpsilonState, R18 = R12-validated batch + vectorized pre_mat matmul + final fused
// into batch via device-scope atomic counter (2 launches).
//  R17 post-mortem: coop-fused kernel = 100us (sum of parts; grid.sync cheap) but
//  coop launch overhead ~76us vs ~34us for the 3-launch graph -> coop reverted.
//  Instruction count on pre_mat: mm64f = 2 scalar LDS reads/FMA = 8192 LDS issues
//  on one pipe ~ 20us (half of pre_mat). Fix: thread = 1 row x 4 adjacent cols,
//  B via b128, A via 4-way broadcast; per-element k-order unchanged (bitwise same).
//  batch: byte-identical R12 pfPR64q (40.3us, VGPR 52, no spill). final: last
//  batch block (atomicAdd counter == 131) runs final_body; producers threadfence;
//  consumer reads lo/lecA via __hip_atomic_load AGENT scope (XCD L2 safety).
// Structure: pre_mat(2x1024) -> batch+final(132x256). Validated math unchanged:
//  - Pf([[A,-I],[I,D]]) = Pf(A)*Pf(D+A^-1)  [R3]   - Ainv 1st-order Neumann [R7]
//  - closed-form bidiagonal Minv f(r,c) [R4]       - sigma-shifted pre-Pf (+pi) [R7]

typedef double2 dcx;
typedef float2 cf;
#define PI_ 3.14159265358979323846
// pair-granular swizzle: column-pair index XORed with row(&31), pair stays adjacent
#define SIDX16(i,j) (((i) << 6) | (((((j) >> 1) ^ ((i) & 31)) << 1) | ((j) & 1)))

__device__ __forceinline__ dcx dmk(double re, double im){ dcx c; c.x=re; c.y=im; return c; }
__device__ __forceinline__ dcx dmul(dcx a, dcx b){ return dmk(a.x*b.x - a.y*b.y, a.x*b.y + a.y*b.x); }

__device__ __forceinline__ double bf2d(unsigned short u){
  union { unsigned u; float f; } cv; cv.u = ((unsigned)u) << 16; return (double)cv.f;
}
__device__ __forceinline__ unsigned short d2bf(double v){
  float f = (float)v;
  union { float f; unsigned u; } cv; cv.f = f;
  unsigned u = cv.u;
  u = (u + 0x7FFFu + ((u >> 16) & 1u)) >> 16;
  return (unsigned short)u;
}
// mode: 0 = bf16, 1 = float32, 2 = float64 (probe buffer first element is +-1.0)
__device__ __forceinline__ int detect_mode(const void* p){
  unsigned w0 = *(const unsigned*)p;
  if ((w0 & 0x7FFFFFFFu) == 0x3F800000u) return 1;
  if ((w0 & 0x7FFFu) == 0x3F80u) return 0;
  return 2;
}
__device__ __forceinline__ double ldv(const void* p, int idx, int mode){
  if (mode == 0) return bf2d(((const unsigned short*)p)[idx]);
  if (mode == 1) return (double)((const float*)p)[idx];
  return ((const double*)p)[idx];
}
// device-coherent double load (cross-block, cross-XCD safe)
__device__ __forceinline__ double ldc(const double* p){
  return __hip_atomic_load(p, __ATOMIC_RELAXED, __HIP_MEMORY_SCOPE_AGENT);
}
__device__ __forceinline__ dcx ldc2(const dcx* p){
  dcx r; r.x = ldc(&p->x); r.y = ldc(&p->y); return r;
}

// ---------------- 64x64 fp32 matmul in LDS: C = scale*A*B (1024 threads, R18) -----
// Thread t: row i = 4*(t>>6) + ((t&63)>>4), cols 4*cL..4*cL+3 (cL = t&15).
// A-read: 4 addrs/wave (broadcast groups, ~4-way conflict). B-read: b128,
// 16 distinct addrs x 4 broadcast groups. Per-element k-order identical to R9.
__device__ void mm64f_1024(float* C, const float* A, const float* B, float scale){
  const int t = threadIdx.x;
  const int w = t >> 6, L = t & 63;
  const int i = 4*w + (L >> 4);
  const int j4 = (L & 15) << 2;
  const float* Ar = A + i*64;
  float4 acc; acc.x = acc.y = acc.z = acc.w = 0.f;
  #pragma unroll 8
  for (int k = 0; k < 64; ++k) {
    float a = Ar[k];
    float4 b = *(const float4*)(B + k*64 + j4);
    acc.x += a*b.x; acc.y += a*b.y; acc.z += a*b.z; acc.w += a*b.w;
  }
  acc.x *= scale; acc.y *= scale; acc.z *= scale; acc.w *= scale;
  *(float4*)(C + i*64 + j4) = acc;
}

// ---------------- pre_mat: one block per channel, 1024 threads (R9-validated) ------
__global__ __launch_bounds__(1024) void pre_mat(
    const void* __restrict__ h1, const void* __restrict__ h2, const void* __restrict__ s0,
    cf* Apx, cf* Czpx, cf* AinvG, dcx* lec_base, int* cnt)
{
  const int px = blockIdx.x;
  const int t = threadIdx.x;
  const int lane = t & 63, wv = t >> 6;          // 16 waves
  const float is2 = 0.70710678118654752440f;
  const int mode = detect_mode(s0);
  const void* H = (px == 0) ? h1 : h2;

  if (px == 0 && t == 0) *cnt = 0;               // reset batch completion counter

  __shared__ __align__(16) unsigned char SH[49664];
  float* Kf = (float*)SH;                    // 16384: K -> (later) RM
  float* Ef = (float*)(SH + 16384);          // 16384: K^2/2 -> E -> M|T1
  cf*   Rc  = (cf*)(SH + 32768);             // 16384: R (64x32)
  cf*   Msl = (cf*)(SH + 16384);             // 8192: M (alias Ef lower)
  cf*   Tsl = (cf*)(SH + 16384 + 8192);      // 8192: T1 -> Mi
  cf*   RMc = (cf*)SH;                       // 16384: RM (alias Kf, after Cz write)
  cf*   ALDS = (cf*)(SH + 16384);            // 32768: A copy (over Ef+Rc, post-RM)
  double* ssh = (double*)(SH + 49152);       // 256
  double* red = (double*)(SH + 49408);       // 128 = 16 doubles (one per wave)
  __shared__ double le_sh;

  if (t < 32) {
    double a = ldv(s0, t, mode);
    double b = ldv(s0, (t + 1) & 31, mode);
    double zz = a * b;
    double s = (zz >= 0.0) ? 1.0 : -1.0;
    if (t == 31) s = (px == 0) ? -s : s;     // sgn[-1] *= -PX
    ssh[t] = s;
  }
  double k2 = 0.0;
  for (int e = t; e < 4096; e += 1024) {
    int i = e >> 6, j = e & 63;
    float kv = (float)(0.5 * (ldv(H, i*64 + j, mode) - ldv(H, j*64 + i, mode)));
    Kf[e] = kv;
    k2 += (double)kv * (double)kv;
  }
  #pragma unroll
  for (int off = 32; off > 0; off >>= 1) k2 += __shfl_down(k2, off, 64);
  if (lane == 0) red[wv] = k2;
  __syncthreads();
  if (t == 0) {
    double acc = 0.0;
    #pragma unroll
    for (int w = 0; w < 16; ++w) acc += red[w];
    le_sh = -acc / 16.0;
  }
  mm64f_1024(Ef, Kf, Kf, 0.5f);
  __syncthreads();
  for (int e = t; e < 4096; e += 1024) {
    int i = e >> 6, j = e & 63;
    Ef[e] += Kf[e] + ((i == j) ? 1.f : 0.f);   // E = I + K + K^2/2
  }
  __syncthreads();
  for (int e = t; e < 2048; e += 1024) {       // R = E v
    int r = e >> 5, k = e & 31;
    int a = 2*k + 1, b2 = (2*k + 2) & 63;
    cf z; z.x = Ef[r*64 + b2] * is2; z.y = -(float)ssh[k] * Ef[r*64 + a] * is2;
    Rc[e] = z;
  }
  __syncthreads();
  {                                            // M = v^H R (1024 elems, 1/thread)
    int e = t;
    int c = e >> 5, k = e & 31;
    int a = 2*c + 1, b2 = (2*c + 2) & 63;
    cf Ra = Rc[a*32 + k], Rb = Rc[b2*32 + k];
    float s = (float)ssh[c];
    cf z; z.x = (-Ra.y*s + Rb.x)*is2; z.y = (Ra.x*s + Rb.y)*is2;
    Msl[e] = z;
  }
  __syncthreads();
  {                                            // T1 = (M-I)^2 (1 elem/thread)
    int e = t;
    int i = e >> 5, j = e & 31;
    float ar = 0.f, ai = 0.f;
    for (int k = 0; k < 32; ++k) {
      cf d1 = Msl[i*32 + k]; if (k == i) d1.x -= 1.f;
      cf d2 = Msl[k*32 + j]; if (k == j) d2.x -= 1.f;
      ar += d1.x*d2.x - d1.y*d2.y;
      ai += d1.x*d2.y + d1.y*d2.x;
    }
    cf z; z.x = ar; z.y = ai;
    __syncthreads();
    // Mi = 2I - M + T1 (Neumann)
    cf m = Msl[e];
    cf w; w.x = ((i == j) ? 2.f : 0.f) - m.x + z.x; w.y = -m.y + z.y;
    Tsl[e] = w;
  }
  for (int e = t; e < 4096; e += 1024) {       // Cz = -K/2 + i*Dz
    int r = e >> 6, c = e & 63;
    float vr = -0.5f * Kf[e];
    float vi = 0.f;
    if ((r & 1) && c == ((r + 1) & 63)) vi = (float)ssh[r >> 1];
    else if ((c & 1) && r == ((c + 1) & 63)) vi = -(float)ssh[c >> 1];
    cf z; z.x = vr; z.y = vi;
    Czpx[(size_t)px*4096 + e] = z;
  }
  __syncthreads();
  for (int e = t; e < 2048; e += 1024) {       // RM = R * Mi (into Kf slot)
    int r = e >> 5, j = e & 31;
    float ar = 0.f, ai = 0.f;
    for (int k = 0; k < 32; ++k) {
      cf a = Rc[r*32 + k], b = Tsl[k*32 + j];
      ar += a.x*b.x - a.y*b.y;
      ai += a.x*b.y + a.y*b.x;
    }
    cf z; z.x = ar; z.y = ai;
    RMc[e] = z;
  }
  __syncthreads();
  for (int e = t; e < 4096; e += 1024) {       // A = antisym(Ghz), v-sparse form
    int r = e >> 6, j = e & 63;
    int cj, cr; cf uj, ur;
    if (j & 1) { cj = j >> 1; uj.x = 0.f; uj.y = (float)ssh[cj] * is2; }
    else { cj = ((j >> 1) + 31) & 31; uj.x = is2; uj.y = 0.f; }
    if (r & 1) { cr = r >> 1; ur.x = 0.f; ur.y = (float)ssh[cr] * is2; }
    else { cr = ((r >> 1) + 31) & 31; ur.x = is2; ur.y = 0.f; }
    cf m1 = RMc[r*32 + cj], m2 = RMc[j*32 + cr];
    cf t1; t1.x = m1.x*uj.x - m1.y*uj.y; t1.y = m1.x*uj.y + m1.y*uj.x;
    cf t2; t2.x = m2.x*ur.x - m2.y*ur.y; t2.y = m2.x*ur.y + m2.y*ur.x;
    cf z; z.x = t2.x - t1.x; z.y = t2.y - t1.y;
    Apx[(size_t)px*4096 + e] = z;
    ALDS[e] = z;
  }
  __syncthreads();
  // Ainv = Dz - a_r*a_c*Delta[pmap r][pmap c]; Delta = A - Dz; Dz(r,c) = i*a_r at c==pmap(r)
  for (int e = t; e < 4096; e += 1024) {
    int r = e >> 6, c = e & 63;
    int pr = (r & 1) ? ((r + 1) & 63) : ((r - 1) & 63);
    int pc = (c & 1) ? ((c + 1) & 63) : ((c - 1) & 63);
    float ar = (r & 1) ? (float)ssh[r >> 1] : -(float)ssh[((r - 1) & 63) >> 1];
    float ac = (c & 1) ? (float)ssh[c >> 1] : -(float)ssh[((c - 1) & 63) >> 1];
    cf Ap = ALDS[pr*64 + pc];
    cf d; d.x = Ap.x; d.y = Ap.y;
    if (c == pr) d.y += ar;
    float f = -ar * ac;
    cf z; z.x = f*d.x; z.y = f*d.y;
    if (c == pr) z.y += ar;                    // + Dz(r,c) = i*a_r
    AinvG[(size_t)px*4096 + e] = z;
  }
  if (t == 0) {
    double ps = 1.0;
    for (int k = 0; k < 32; ++k) ps *= ssh[k];
    double phDz = (ps > 0.0) ? PI_ : 0.0;      // Pf(Dz) = -prod(s)
    lec_base[px] = dmk(le_sh, phDz);
  }
}

// ---------------- Parlett-Reid slog-Pfaffian (R12-validated, byte-identical) -------
__device__ void pfPR64q(cf* S, float4* ubuf, double* lab_out, double* ph_out){
  const int t = threadIdx.x;
  const int l = t & 63;
  const int w = t >> 6;
  const int lmask = l & 31;
  const int rbase = l << 6;
  double prodr = 1.0, prodi = 0.0;
  int neg = 0, zflag = 0;
  for (int p = 0; p < 31; ++p) {
    const int l0 = 2*p;
    __syncthreads();                           // publish prior step / build
    cf b1 = S[SIDX16(l, l0)];
    cf b2 = S[SIDX16(l, l0+1)];
    cf a; a.x = __shfl(b2.x, l0, 64); a.y = __shfl(b2.y, l0, 64);
    float am2 = a.x*a.x + a.y*a.y;
    if (am2 < 1e-4f) {                         // uniform rare path: pivot search
      float val = (l >= l0+1) ? (b1.x*b1.x + b1.y*b1.y) : 0.f;  // |S[l][l0]|
      unsigned pk = (__float_as_uint(val) & 0xFFFFFFC0u) | (unsigned)l;
      #pragma unroll
      for (int off = 32; off > 0; off >>= 1) {
        unsigned o = (unsigned)__shfl_xor((int)pk, off, 64);
        if (o > pk) pk = o;
      }
      int q = (int)(pk & 63u);                 // identical in all 4 waves
      if (q > l0+1) {
        __syncthreads();                       // all reads done before swap writes
        if (t < 64) {                          // physical row swap l0+1 <-> q
          cf r1 = S[SIDX16(l0+1, t)], r2 = S[SIDX16(q, t)];
          S[SIDX16(l0+1, t)] = r2; S[SIDX16(q, t)] = r1;
        }
        __syncthreads();
        if (t < 64) {                          // physical col swap
          cf u1 = S[SIDX16(t, l0+1)], u2 = S[SIDX16(t, q)];
          S[SIDX16(t, l0+1)] = u2; S[SIDX16(t, q)] = u1;
        }
        __syncthreads();
        neg ^= 1;
      }
      b1 = S[SIDX16(l, l0)]; b2 = S[SIDX16(l, l0+1)];
      a.x = __shfl(b2.x, l0, 64); a.y = __shfl(b2.y, l0, 64);
      am2 = a.x*a.x + a.y*a.y;
    }
    {                                          // prod *= a (uniform, all threads)
      double nr = prodr*(double)a.x - prodi*(double)a.y;
      double ni = prodr*(double)a.y + prodi*(double)a.x;
      prodr = nr; prodi = ni;
    }
    if (am2 == 0.f) { zflag = 1; continue; }   // uniform: singular step
    float rcp = 1.f/am2;
    cf iv; iv.x = a.x*rcp; iv.y = -a.y*rcp;
    cf w1, w2;                                 // iv folded into lane's border
    w1.x = b1.x*iv.x - b1.y*iv.y; w1.y = b1.x*iv.y + b1.y*iv.x;
    w2.x = b2.x*iv.x - b2.y*iv.y; w2.y = b2.x*iv.y + b2.y*iv.x;
    float4 ub; ub.x = b1.x; ub.y = b1.y; ub.z = b2.x; ub.w = b2.y;
    ubuf[l] = ub;                              // 4 waves, same value: benign
    __syncthreads();                           // ubuf visible
    const int lim = l0 + 2;
    const bool rowok = (l >= lim);
    #pragma unroll
    for (int jj = 0; jj < 8; ++jj) {
      int q2 = p + 1 + jj*4 + w;               // this wave's pair index
      int qc = (q2 > 31) ? 31 : q2;            // clamp: address always valid
      float4 ua  = ubuf[2*qc];                 // u(j),   j = 2*qc  (broadcast)
      float4 ubx = ubuf[2*qc + 1];             // u(j+1)
      int idx = rbase | ((qc ^ lmask) << 1);   // SIDX16(l, 2*qc)
      float4 cur = *(float4*)(S + idx);
      cur.x += w2.x*ua.x  - w2.y*ua.y  - w1.x*ua.z  + w1.y*ua.w;
      cur.y += w2.x*ua.y  + w2.y*ua.x  - w1.x*ua.w  - w1.y*ua.z;
      cur.z += w2.x*ubx.x - w2.y*ubx.y - w1.x*ubx.z + w1.y*ubx.w;
      cur.w += w2.x*ubx.y + w2.y*ubx.x - w1.x*ubx.w - w1.y*ubx.z;
      if (rowok && q2 <= 31) *(float4*)(S + idx) = cur;
    }
  }
  __syncthreads();
  cf z = S[SIDX16(62, 63)];
  double nr = prodr*(double)z.x - prodi*(double)z.y;
  double ni = prodr*(double)z.y + prodi*(double)z.x;
  if (neg) { nr = -nr; ni = -ni; }
  double m2 = nr*nr + ni*ni;
  if (zflag || m2 == 0.0) { *lab_out = -23000.0; *ph_out = 0.0; }
  else { *lab_out = 0.5*log(m2); *ph_out = atan2(ni, nr); }
}

// ---------------- final body (threads < 64), coherent reads of lo/lecA -------------
__device__ void final_body(const void* __restrict__ x, const void* __restrict__ s0,
                           const dcx* __restrict__ lec_base, const dcx* __restrict__ lecA,
                           const dcx* __restrict__ lo, void* __restrict__ out, int out_size)
{
  int b = threadIdx.x;
  if (b >= 64) return;
  const int mode = detect_mode(x);
  double L[2], P[2];
  #pragma unroll
  for (int px = 0; px < 2; ++px) {
    dcx base = lec_base[px];                  // written by pre_mat (prior launch)
    dcx eA = ldc2(&lecA[px]);                 // written by other blocks this launch
    dcx eC = ldc2(&lecA[2 + px]);
    dcx l  = ldc2(&lo[px*64 + b]);
    L[px] = base.x + eA.x + eC.x + l.x;
    P[px] = base.y + eA.y + eC.y + l.y;
  }
  dcx t1 = dmk(L[1], P[1]);                 // minus
  dcx t2 = dmk(L[0], P[0]);                 // plus
  double v = ldv(x, b*32 + 31, mode) * ldv(s0, 31, mode);
  t2.x += log(fabs(v));
  if (v < 0.0) t2.y += PI_;
  double mr = fmax(t1.x, t2.x);
  double e1 = exp(t1.x - mr), e2 = exp(t2.x - mr);
  double zr = e1 * cos(t1.y) + e2 * cos(t2.y);
  double zi = e1 * sin(t1.y) + e2 * sin(t2.y);
  double outr = mr + 0.5 * log(zr*zr + zi*zi);
  double outi = atan2(zi, zr);
  if (mode == 0) {
    unsigned short* o = (unsigned short*)out;
    if (out_size >= 128) { o[2*b] = d2bf(outr); o[2*b + 1] = d2bf(outi); }
    else o[b] = d2bf(outr);
  } else {
    float* o = (float*)out;
    if (out_size >= 128) { o[2*b] = (float)outr; o[2*b + 1] = (float)outi; }
    else o[b] = (float)outr;
  }
}

// ---------------- batch: 0..127 = (px,b); 128..131 = pre-Pf; last block runs final -
__global__ __launch_bounds__(256, 1) void batch_kernel(
    const void* __restrict__ x, const void* __restrict__ s0,
    const cf* __restrict__ Apx, const cf* __restrict__ Czpx,
    const cf* __restrict__ AinvG, const dcx* __restrict__ lec_base,
    dcx* lo, dcx* lecA, int* cnt, void* out, int out_size)
{
  __shared__ __align__(16) unsigned char SH[36608];
  cf* Sp      = (cf*)SH;                      // 32768: SIDX16 64x64
  double* ssh = (double*)(SH + 32768);        // 256
  dcx* rho    = (dcx*)(SH + 33024);           // 1024
  dcx* uu     = (dcx*)(SH + 34048);           // 1024
  int* cidx   = (int*)(SH + 35072);           // 256
  float* pref = (float*)(SH + 35328);         // 132 (+pad)
  float4* ubuf = (float4*)(SH + 35472);       // 1024: border broadcast table
  __shared__ int is_last;
  const int t = threadIdx.x;
  const int pb = blockIdx.x;
  const double inv_sqrt2 = 0.70710678118654752440;

  if (pb >= 128) {          // pre-Pfaffians, sigma-shifted (det sigma = -1 -> +pi)
    const int idx = pb - 128;
    const cf* src = (idx < 2) ? (Apx + (size_t)idx*4096) : (Czpx + (size_t)(idx-2)*4096);
    for (int e = t; e < 4096; e += 256) {
      int i = e >> 6, j = e & 63;
      Sp[SIDX16(i, j)] = src[((i + 1) & 63)*64 + ((j + 1) & 63)];
    }
  } else {
    const int px = pb >> 6, b = pb & 63;
    const int mode = detect_mode(x);

    if (t < 32) {
      double a = ldv(x, b*32 + t, mode);
      double b2 = ldv(x, b*32 + ((t + 1) & 31), mode);
      double zz = a * b2;
      double s = (zz >= 0.0) ? 1.0 : -1.0;
      if (t == 31) s = (px == 0) ? -s : s;
      ssh[t] = s;
    }
    __syncthreads();
    if (t < 64) {
      int r = t;
      if (r & 1) rho[r] = dmk(inv_sqrt2, 0.0);
      else {
        int k = r >> 1;
        double pim = -inv_sqrt2;
        if (px == 1 && k == 31) pim = inv_sqrt2;
        rho[r] = dmk(0.0, pim);
      }
      int j = t;
      if (j & 1) { cidx[j] = j >> 1; uu[j] = dmk(0.0, ssh[j >> 1] * inv_sqrt2); }
      else { cidx[j] = ((j >> 1) + 31) & 31; uu[j] = dmk(inv_sqrt2, 0.0); }
    }
    if (t == 0) {
      float pp = 1.f;
      pref[0] = 1.f;
      for (int c = 0; c < 32; ++c) {
        float q = (px == 1 && c == 30) ? 1.f : -1.f;
        pp *= q * (float)ssh[c];
        pref[c + 1] = pp;
      }
    }
    __syncthreads();
    // C = D + Ainv; D[a][b] = rho_b u_a Minv[b/2][c_a] - rho_a u_b Minv[a/2][c_b],
    // Minv[r][c] = -i*f(r,c) closed form (R4/R5-validated pieces).
    for (int e = t; e < 4096; e += 256) {
      int a = e >> 6, bb = e & 63;
      int r1 = bb >> 1, c1 = cidx[a];
      float f1 = ((c1 < r1) ? -1.f : 1.f) * (((c1 - r1) & 1) ? -1.f : 1.f)
                 * pref[r1] * pref[c1] * (float)ssh[c1];
      int r2 = a >> 1, c2 = cidx[bb];
      float f2 = ((c2 < r2) ? -1.f : 1.f) * (((c2 - r2) & 1) ? -1.f : 1.f)
                 * pref[r2] * pref[c2] * (float)ssh[c2];
      dcx m1 = dmk(0.0, -(double)f1);
      dcx m2 = dmk(0.0, -(double)f2);
      dcx t1 = dmul(dmul(rho[bb], uu[a]), m1);
      dcx t2 = dmul(dmul(rho[a], uu[bb]), m2);
      cf av = AinvG[(size_t)px*4096 + e];
      cf z;
      z.x = (float)((double)av.x + t1.x - t2.x);
      z.y = (float)((double)av.y + t1.y - t2.y);
      Sp[SIDX16(a, bb)] = z;
    }
  }
  double lab, ph;
  pfPR64q(Sp, ubuf, &lab, &ph);     // entry barrier inside (loop top)
  if (t == 0) {
    if (pb >= 128) lecA[pb - 128] = dmk(lab, ph + PI_);
    else lo[pb] = dmk(lab, ph);
    __threadfence();                // release: publish result to device scope
    int old = atomicAdd(cnt, 1);    // device-scope by default
    is_last = (old == 131) ? 1 : 0;
  }
  __syncthreads();
  if (is_last) {                    // this block saw all 132 results published
    __threadfence();                // acquire side
    final_body(x, s0, lec_base, lecA, lo, out, out_size);
  }
}

extern "C" void kernel_launch(void* const* d_in, const int* in_sizes, int n_in,
                              void* d_out, int out_size, void* d_ws, size_t ws_size,
                              hipStream_t stream)
{
  const void* x  = d_in[0];
  const void* s0 = d_in[1];
  const void* h1 = d_in[2];
  const void* h2 = d_in[3];

  cf*  Apx   = (cf*)d_ws;                   // 2*4096 cf
  cf*  Czpx  = Apx + 8192;                  // 2*4096 cf
  cf*  AinvG = Czpx + 8192;                 // 2*4096 cf
  dcx* lec_base = (dcx*)(AinvG + 8192);     // 2
  dcx* lecA  = lec_base + 2;                // 4
  dcx* lo    = lecA + 4;                    // 128
  int* cnt   = (int*)(lo + 128);            // 1
  // ~0.2 MB of d_ws

  pre_mat<<<dim3(2), dim3(1024), 0, stream>>>(h1, h2, s0, Apx, Czpx, AinvG, lec_base, cnt);
  batch_kernel<<<dim3(132), dim3(256), 0, stream>>>(x, s0, Apx, Czpx, AinvG, lec_base,
                                                    lo, lecA, cnt, d_out, out_size);
}